// Round 1
// baseline (5060.270 us; speedup 1.0000x reference)
//
#include <hip/hip_runtime.h>

#define IMG 256
#define NIMG 16

// ---------------------------------------------------------------------------
// Transpose weights from [o][u][v] (o=16 channels) to tap-major [u*K+v][o]
// so all 16 channel weights for one tap are contiguous (64B, one cache line,
// thread-uniform load in the conv kernel).
// ---------------------------------------------------------------------------
__global__ void wtrans_kernel(const float* __restrict__ w, float* __restrict__ wt, int K2) {
    int total = 16 * K2;
    for (int idx = blockIdx.x * blockDim.x + threadIdx.x; idx < total;
         idx += gridDim.x * blockDim.x) {
        int t = idx >> 4;   // tap index u*K+v
        int o = idx & 15;   // channel
        wt[idx] = w[o * K2 + t];
    }
}

// ---------------------------------------------------------------------------
// One block = one image n x one 16x16 tile of output positions x one channel
// group of CPT channels. Each thread: one output position, CPT accumulators.
// Inner loop per tap: 1 per-lane x load (L1/L2 hit) + CPT uniform w loads
// (contiguous, scalar-cache) + CPT FMAs.
// Epilogue: y^2, wave shfl-reduce, LDS combine, one atomicAdd per (n,o).
// ---------------------------------------------------------------------------
template <int CPT>
__global__ __launch_bounds__(256) void conv_energy_kernel(
    const float* __restrict__ x, const float* __restrict__ wt,
    float* __restrict__ E,   // [16 n][16 o] partial sums of y^2 for this scale
    int K, int Hout, int tilesJ) {
    const int tilesPerImg = tilesJ * tilesJ;
    const int cg = blockIdx.y;                 // channel group
    const int n  = blockIdx.x / tilesPerImg;
    const int t  = blockIdx.x % tilesPerImg;
    const int ti = t / tilesJ, tj = t % tilesJ;
    const int li = threadIdx.x >> 4, lj = threadIdx.x & 15;
    int i = ti * 16 + li, j = tj * 16 + lj;
    const bool active = (i < Hout) && (j < Hout);
    if (i > Hout - 1) i = Hout - 1;   // clamp so loads stay in-bounds
    if (j > Hout - 1) j = Hout - 1;

    const float* xb = x + (size_t)n * (IMG * IMG) + (size_t)i * IMG + j;
    const float* wg = wt + cg * CPT;

    float acc[CPT];
#pragma unroll
    for (int c = 0; c < CPT; ++c) acc[c] = 0.0f;

    for (int u = 0; u < K; ++u) {
        const float* xr = xb + (size_t)u * IMG;
        const float* wr = wg + (size_t)u * K * 16;
#pragma unroll 4
        for (int v = 0; v < K; ++v) {
            const float xv = xr[v];
            const float* wp = wr + v * 16;
#pragma unroll
            for (int c = 0; c < CPT; ++c)
                acc[c] = fmaf(xv, wp[c], acc[c]);
        }
    }

    __shared__ float part[CPT];
    if (threadIdx.x < CPT) part[threadIdx.x] = 0.0f;
    __syncthreads();
#pragma unroll
    for (int c = 0; c < CPT; ++c) {
        float e = active ? acc[c] * acc[c] : 0.0f;
#pragma unroll
        for (int m = 1; m < 64; m <<= 1) e += __shfl_xor(e, m, 64);
        if ((threadIdx.x & 63) == 0) atomicAdd(&part[c], e);
    }
    __syncthreads();
    if (threadIdx.x < CPT)
        atomicAdd(&E[n * 16 + cg * CPT + threadIdx.x], part[threadIdx.x]);
}

// ---------------------------------------------------------------------------
// out[n][c][s] = (E[s][n][c] + E[s][n][c+8]) / (P_s * scale_s),  512 outputs.
// ---------------------------------------------------------------------------
__global__ void finalize_kernel(const float* __restrict__ E, float* __restrict__ out) {
    int idx = threadIdx.x;
    if (idx >= 512) return;
    int s = idx & 3, c = (idx >> 2) & 7, n = idx >> 5;
    // scale_s * Hout_s^2:
    // s0: 1*232^2 = 53824   s1: 2*208^2 = 86528
    // s2: 4*160^2 = 102400  s3: 8*64^2  = 32768
    float denom;
    if (s == 0)      denom = 53824.0f;
    else if (s == 1) denom = 86528.0f;
    else if (s == 2) denom = 102400.0f;
    else             denom = 32768.0f;
    float v = (E[s * 256 + n * 16 + c] + E[s * 256 + n * 16 + c + 8]) / denom;
    out[idx] = v;
}

extern "C" void kernel_launch(void* const* d_in, const int* in_sizes, int n_in,
                              void* d_out, int out_size, void* d_ws, size_t ws_size,
                              hipStream_t stream) {
    const float* x = (const float*)d_in[0];
    const float* w[4] = {(const float*)d_in[1], (const float*)d_in[2],
                         (const float*)d_in[3], (const float*)d_in[4]};
    const int Ks[4] = {25, 49, 97, 193};

    float* E = (float*)d_ws;          // 4 scales x 16 n x 16 o = 1024 floats
    float* wt_base = E + 1024;        // transposed weights, ~3.2 MB total
    size_t wt_off[4];
    size_t off = 0;
    for (int s = 0; s < 4; ++s) { wt_off[s] = off; off += (size_t)16 * Ks[s] * Ks[s]; }

    hipMemsetAsync(E, 0, 1024 * sizeof(float), stream);

    for (int s = 0; s < 4; ++s) {
        int K2 = Ks[s] * Ks[s];
        int total = 16 * K2;
        int blocks = (total + 255) / 256;
        wtrans_kernel<<<blocks, 256, 0, stream>>>(w[s], wt_base + wt_off[s], K2);
    }

    for (int s = 0; s < 4; ++s) {
        int K = Ks[s];
        int Hout = 256 - K + 1;
        int tilesJ = (Hout + 15) / 16;
        int blocks = NIMG * tilesJ * tilesJ;
        if (s < 3) {
            conv_energy_kernel<16><<<dim3(blocks, 1), 256, 0, stream>>>(
                x, wt_base + wt_off[s], E + s * 256, K, Hout, tilesJ);
        } else {
            // K=193 has only 4096 positions/image -> split channels 2x for occupancy
            conv_energy_kernel<8><<<dim3(blocks, 2), 256, 0, stream>>>(
                x, wt_base + wt_off[s], E + s * 256, K, Hout, tilesJ);
        }
    }

    finalize_kernel<<<1, 512, 0, stream>>>(E, (float*)d_out);
}

// Round 2
// 1560.214 us; speedup vs baseline: 3.2433x; 3.2433x over previous
//
#include <hip/hip_runtime.h>
#include <hip/hip_bf16.h>

typedef __attribute__((ext_vector_type(8))) short short8v;
typedef __attribute__((ext_vector_type(4))) float f32x4;

#define IMG 256
#define NIMG 16
#define XB_ELEMS (NIMG * IMG * IMG)   // 1048576
#define XB_PAD 1024                   // zero tail: A-loads overrun <= ~300B past last image

struct ConvParams {
  int blkStart[5];   // cumulative block starts in dispatch order
  int sOf[4];        // dispatch position -> scale id
  int K[4], NSV[4], Hout[4], IG[4], TG[4], Ga[4], JBa[4];
  unsigned wpOff[4]; // packed-weight element offsets per scale
};

// ---------------------------------------------------------------------------
// f32 -> bf16 image convert + zero tail pad.
// ---------------------------------------------------------------------------
__global__ void xconvert_kernel(const float* __restrict__ x,
                                __hip_bfloat16* __restrict__ xb) {
  int i = blockIdx.x * blockDim.x + threadIdx.x;
  if (i < XB_ELEMS)             xb[i] = __float2bfloat16(x[i]);
  else if (i < XB_ELEMS + XB_PAD) xb[i] = __float2bfloat16(0.0f);
}

// ---------------------------------------------------------------------------
// Pack weights into MFMA B-fragment order with 8 shifted copies (sigma = j%8).
// Layout: wp[((sig*K + u)*NSV + sv)*512 + lane*8 + e]
//   B[k][n]: n = lane&15 (channel), k = (lane>>4)*8 + e (tap within 32-slice)
//   value = w[o][u][v] with v = sv*32 + k - sig, zero outside [0,K).
// ---------------------------------------------------------------------------
__global__ void wpack_kernel(const float* __restrict__ w,
                             __hip_bfloat16* __restrict__ wp,
                             int K, int NSV, int total) {
  for (int idx = blockIdx.x * blockDim.x + threadIdx.x; idx < total;
       idx += gridDim.x * blockDim.x) {
    int e    = idx & 7;
    int lane = (idx >> 3) & 63;
    int rest = idx >> 9;
    int sv   = rest % NSV; rest /= NSV;
    int u    = rest % K;
    int sig  = rest / K;
    int o    = lane & 15;
    int v    = sv * 32 + (lane >> 4) * 8 + e - sig;
    float val = (v >= 0 && v < K) ? w[(o * K + u) * K + v] : 0.0f;
    wp[idx] = __float2bfloat16(val);
  }
}

// ---------------------------------------------------------------------------
// Implicit-GEMM conv + energy, all 4 scales in one launch.
// Wave job: (scale, image n, i-group ig (G tiles of 16 rows), sigma, t-group).
// rb = absolute x-row offset: one A-frag serves all G row-groups (u = rb-16g).
// acc[g][jb] = 16 rows x 16 channels for output column j = sigma + 8*(t0+jb).
// ---------------------------------------------------------------------------
__global__ __launch_bounds__(256, 4) void conv_mfma_kernel(
    const ushort* __restrict__ xb, const ushort* __restrict__ wp,
    float* __restrict__ E, ConvParams P) {
  int p = 0, b = blockIdx.x;
  while (p < 3 && b >= P.blkStart[p + 1]) p++;
  const int s  = P.sOf[p];
  const int bl = b - P.blkStart[p];
  const int wv = threadIdx.x >> 6, lane = threadIdx.x & 63;
  const int K = P.K[s], NSV = P.NSV[s], Hout = P.Hout[s];
  const int IG = P.IG[s], TG = P.TG[s], Ga = P.Ga[s], JBa = P.JBa[s];

  const int sig = (bl & 1) * 4 + wv;
  int r2 = bl >> 1;
  const int tg = r2 % TG; r2 /= TG;
  const int ig = r2 % IG;
  const int n  = r2 / IG;
  const int i0 = ig * Ga * 16;
  const int t0 = tg * JBa;

  const int lr = lane & 15;       // A row / C channel-col index
  const int lg = lane >> 4;       // k-group
  const int colBase = 8 * (t0 + lg);
  const ushort* Wbase = wp + P.wpOff[s] + (unsigned)(sig * K) * (NSV * 512) + lane * 8;
  const ushort* Xn = xb + (n << 16);

  f32x4 acc[4][4];
#pragma unroll
  for (int g = 0; g < 4; ++g)
#pragma unroll
    for (int jb = 0; jb < 4; ++jb) acc[g][jb] = (f32x4)(0.0f);

  const int rbEnd = K + 16 * (Ga - 1);
  for (int rb = 0; rb < rbEnd; ++rb) {
    int gvmask = 0;
#pragma unroll
    for (int g = 0; g < 4; ++g) {
      int u = rb - 16 * g;
      if (g < Ga && u >= 0 && u < K && (i0 + 16 * g) < Hout) gvmask |= 1 << g;
    }
    if (!gvmask) continue;

    int rr = i0 + rb + lr;                 // x row (clamped; invalid rows masked later)
    rr = rr > 255 ? 255 : rr;
    const ushort* Arow = Xn + (rr << 8) + colBase;

    for (int sv = 0; sv < NSV; ++sv) {
      short8v bf[4];
#pragma unroll
      for (int g = 0; g < 4; ++g) {
        if (gvmask & (1 << g)) {
          int u = rb - 16 * g;
          bf[g] = *(const short8v*)(Wbase + (u * NSV + sv) * 512);
        }
      }
#pragma unroll
      for (int jb = 0; jb < 4; ++jb) {
        if (jb < JBa) {
          short8v af = *(const short8v*)(Arow + sv * 32 + jb * 8);
#pragma unroll
          for (int g = 0; g < 4; ++g) {
            if (gvmask & (1 << g)) {
              acc[g][jb] = __builtin_amdgcn_mfma_f32_16x16x32_bf16(
                  af, bf[g], acc[g][jb], 0, 0, 0);
            }
          }
        }
      }
    }
  }

  // Epilogue: e = sum of y^2 over this wave's valid outputs, per channel (lr).
  float esum = 0.0f;
#pragma unroll
  for (int g = 0; g < 4; ++g)
#pragma unroll
    for (int jb = 0; jb < 4; ++jb)
#pragma unroll
      for (int r = 0; r < 4; ++r) {
        int i_out = i0 + 16 * g + 4 * lg + r;
        int j     = sig + 8 * (t0 + jb);
        float v = acc[g][jb][r];
        esum += (i_out < Hout && j < Hout) ? v * v : 0.0f;
      }
  esum += __shfl_xor(esum, 16, 64);
  esum += __shfl_xor(esum, 32, 64);
  if (lg == 0) atomicAdd(&E[s * 256 + n * 16 + lr], esum);
}

// ---------------------------------------------------------------------------
// out[n][c][s] = (E[s][n][c] + E[s][n][c+8]) / (Hout_s^2 * scale_s)
// ---------------------------------------------------------------------------
__global__ void finalize_kernel(const float* __restrict__ E, float* __restrict__ out) {
  int idx = threadIdx.x;
  if (idx >= 512) return;
  int s = idx & 3, c = (idx >> 2) & 7, n = idx >> 5;
  float denom;
  if (s == 0)      denom = 53824.0f;    // 1*232^2
  else if (s == 1) denom = 86528.0f;    // 2*208^2
  else if (s == 2) denom = 102400.0f;   // 4*160^2
  else             denom = 32768.0f;    // 8*64^2
  out[idx] = (E[s * 256 + n * 16 + c] + E[s * 256 + n * 16 + c + 8]) / denom;
}

extern "C" void kernel_launch(void* const* d_in, const int* in_sizes, int n_in,
                              void* d_out, int out_size, void* d_ws, size_t ws_size,
                              hipStream_t stream) {
  const float* x = (const float*)d_in[0];
  const float* w[4] = {(const float*)d_in[1], (const float*)d_in[2],
                       (const float*)d_in[3], (const float*)d_in[4]};

  static const int Ks[4]   = {25, 49, 97, 193};
  static const int NSVs[4] = {1, 2, 4, 7};      // ceil((K+7)/32)
  static const int Houts[4]= {232, 208, 160, 64};
  static const int MTs[4]  = {15, 13, 10, 4};
  static const int Gas[4]  = {4, 4, 4, 2};
  static const int JBas[4] = {4, 4, 4, 2};

  char* wsb = (char*)d_ws;
  float* E = (float*)wsb;                                        // 4 KB
  __hip_bfloat16* xb = (__hip_bfloat16*)(wsb + 4096);            // 2 MB + pad
  __hip_bfloat16* wpb = (__hip_bfloat16*)(wsb + 4096 + (size_t)(XB_ELEMS + XB_PAD) * 2);

  ConvParams P;
  unsigned off = 0;
  int blocksPer[4];
  for (int s = 0; s < 4; ++s) {
    P.K[s] = Ks[s]; P.NSV[s] = NSVs[s]; P.Hout[s] = Houts[s];
    P.Ga[s] = Gas[s]; P.JBa[s] = JBas[s];
    P.IG[s] = (MTs[s] + Gas[s] - 1) / Gas[s];
    int tcnt = (Houts[s] + 7) / 8;
    P.TG[s] = (tcnt + JBas[s] - 1) / JBas[s];
    P.wpOff[s] = off;
    off += 8u * Ks[s] * NSVs[s] * 512;
    blocksPer[s] = NIMG * P.IG[s] * P.TG[s] * 2;
  }
  static const int order[4] = {3, 2, 1, 0};     // long jobs dispatch first
  int cum = 0;
  for (int p = 0; p < 4; ++p) {
    P.sOf[p] = order[p];
    P.blkStart[p] = cum;
    cum += blocksPer[order[p]];
  }
  P.blkStart[4] = cum;

  hipMemsetAsync(E, 0, 1024 * sizeof(float), stream);

  xconvert_kernel<<<(XB_ELEMS + XB_PAD + 255) / 256, 256, 0, stream>>>(x, xb);

  for (int s = 0; s < 4; ++s) {
    int total = 8 * Ks[s] * NSVs[s] * 512;
    wpack_kernel<<<(total + 255) / 256, 256, 0, stream>>>(
        w[s], wpb + P.wpOff[s], Ks[s], NSVs[s], total);
  }

  conv_mfma_kernel<<<cum, 256, 0, stream>>>((const ushort*)xb, (const ushort*)wpb, E, P);

  finalize_kernel<<<1, 512, 0, stream>>>(E, (float*)d_out);
}

// Round 3
// 496.904 us; speedup vs baseline: 10.1836x; 3.1399x over previous
//
#include <hip/hip_runtime.h>
#include <hip/hip_bf16.h>

typedef __attribute__((ext_vector_type(8))) short short8v;
typedef __attribute__((ext_vector_type(4))) float f32x4;

#define IMG 256
#define NIMG 16
#define XB_ELEMS (NIMG * IMG * IMG)

// LDS x-tile: 32 rows x 320 cols (bf16), skewed row layout to balance banks.
#define LSTRIDE 768               // bytes per LDS row (640 data + 128 skew slack)
#define LROWS   32
#define BBUF    (LROWS * LSTRIDE) // 24576 bytes per buffer
#define NI      (BBUF / 1024)     // 24 global_load_lds (1KB) per chunk

// packed-weight element offsets (8 sigmas x (K+32) u-rows x NSV x 512)
#define WOFF0 0u
#define WOFF1 233472u       // + 8*57*1*512
#define WOFF2 897024u       // + 8*81*2*512
#define WOFF3 3010560u      // + 8*129*4*512
#define WELEMS 9461760u     // + 8*225*7*512

// ---------------------------------------------------------------------------
// f32 -> bf16 image convert.
// ---------------------------------------------------------------------------
__global__ void xconvert_kernel(const float* __restrict__ x,
                                __hip_bfloat16* __restrict__ xb) {
  int i = blockIdx.x * blockDim.x + threadIdx.x;
  if (i < XB_ELEMS) xb[i] = __float2bfloat16(x[i]);
}

// ---------------------------------------------------------------------------
// Pack weights: wp[sig][u_pad][sv][lane*8+e], u_pad in [0,K+32), zero outside
// u in [0,K) and v = 32*sv + k - sig outside [0,K).  k = 8*(lane>>4)+e.
// ---------------------------------------------------------------------------
__global__ void wpack_kernel(const float* __restrict__ w,
                             unsigned short* __restrict__ wp,
                             int K, int NSV, int total) {
  for (int idx = blockIdx.x * blockDim.x + threadIdx.x; idx < total;
       idx += gridDim.x * blockDim.x) {
    int e    = idx & 7;
    int lane = (idx >> 3) & 63;
    int rest = idx >> 9;
    int sv   = rest % NSV; rest /= NSV;
    int up   = rest % (K + 32);
    int sig  = rest / (K + 32);
    int o    = lane & 15;
    int u    = up - 16;
    int v    = sv * 32 + (lane >> 4) * 8 + e - sig;
    float val = (u >= 0 && u < K && v >= 0 && v < K) ? w[(o * K + u) * K + v] : 0.0f;
    __hip_bfloat16 h = __float2bfloat16(val);
    wp[idx] = *(unsigned short*)&h;
  }
}

// ---------------------------------------------------------------------------
// Per-scale conv+energy. Block = (sigma, n, 32-row group). sigma = bl&7 so
// blockIdx%8 -> XCD: each XCD only ever reads its own sigma's weight slices
// (L2-resident). Waves split output columns (JBA 8-col slots each).
// x chunks (16 rb) double-buffered in LDS via global_load_lds.
// ---------------------------------------------------------------------------
template <int K, int NSV, int JBA, int WAVES, int HOUT, int IG, unsigned WOFF, int SIDX>
__device__ __forceinline__ void conv_scale(int bl,
                                           const unsigned short* __restrict__ xb,
                                           const unsigned short* __restrict__ wp,
                                           float* __restrict__ E, char* lds) {
  constexpr int RBEND = K + 16;
  constexpr int NCH   = (RBEND + 15) / 16;
  constexpr int TAIL  = RBEND - 16 * (NCH - 1);
  constexpr int M     = (NI + WAVES - 1) / WAVES;   // stage instrs per wave
  constexpr int WROW  = NSV * 512;                  // weight row stride (elems)
  constexpr unsigned WSLICE = (unsigned)(K + 32) * WROW;

  const int wv = threadIdx.x >> 6, lane = threadIdx.x & 63;
  const int sig = bl & 7;
  int rest = bl >> 3;
  const int ig = rest % IG, n = rest / IG;
  const int i0 = ig * 32;
  const int lr = lane & 15, lg = lane >> 4;
  const bool act = (wv < WAVES);

  const unsigned short* Wbase = wp + WOFF + (unsigned)sig * WSLICE + (unsigned)lane * 8;
  const unsigned short* Xn = xb + ((unsigned)n << 16);
  unsigned short* lds0 = (unsigned short*)lds;
  unsigned short* lds1 = (unsigned short*)(lds + BBUF);

  // Stage chunk: LDS written linearly (1KB per instr); per-lane global source
  // encodes the skewed layout: physical byte P -> row = P/768,
  // col2 = P%768 - 16*(row&7), clamped into the image.
  auto stage = [&](unsigned short* lb, int chunk) {
#pragma unroll
    for (int k2 = 0; k2 < M; ++k2) {
      int ib = wv + WAVES * k2;
      if (ib >= NI) ib = 0;                       // benign duplicate
      int P = ib * 1024 + lane * 16;
      int row = P / LSTRIDE;
      int col2 = (P - row * LSTRIDE) - ((row & 7) << 4);
      int colE = col2 >> 1;
      if (colE < 0) colE = 0;
      if (colE > 248) colE = 248;
      int grow = i0 + chunk * 16 + row;
      if (grow > 255) grow = 255;
      const unsigned short* gp = Xn + (grow << 8) + colE;
      __builtin_amdgcn_global_load_lds(
          (const __attribute__((address_space(1))) unsigned int*)(const void*)gp,
          (__attribute__((address_space(3))) unsigned int*)(void*)(lb + (P >> 1)),
          16, 0, 0);
    }
  };

  f32x4 acc[2][JBA];
#pragma unroll
  for (int g = 0; g < 2; ++g)
#pragma unroll
    for (int jb = 0; jb < JBA; ++jb) acc[g][jb] = (f32x4)(0.0f);

  if (act) stage(lds0, 0);
  asm volatile("s_waitcnt vmcnt(0)" ::: "memory");
  __builtin_amdgcn_s_barrier();
  __builtin_amdgcn_sched_barrier(0);

  const int cbyte = ((wv * JBA + lg) << 4);       // wave/lane column byte base

  for (int c = 0; c < NCH; ++c) {
    unsigned short* lb = (c & 1) ? lds1 : lds0;
    if (act) {
      if (c + 1 < NCH) stage((c & 1) ? lds0 : lds1, c + 1);
      const int RL = (c == NCH - 1) ? TAIL : 16;
      const unsigned short* Wc = Wbase + (unsigned)(c * 16) * WROW;
#pragma unroll 2
      for (int rbL = 0; rbL < RL; ++rbL) {
        const int rowLoc = rbL + lr;
        const char* abase = (const char*)lb + rowLoc * LSTRIDE +
                            ((rowLoc & 7) << 4) + cbyte;
        const unsigned short* Wr1 = Wc + rbL * WROW;        // g=1 (rows i0+16..31)
        const unsigned short* Wr0 = Wr1 + 16 * WROW;        // g=0 (rows i0..15)
#pragma unroll
        for (int sv = 0; sv < NSV; ++sv) {
          short8v b0 = *(const short8v*)(Wr0 + sv * 512);
          short8v b1 = *(const short8v*)(Wr1 + sv * 512);
          short8v a_[JBA];
#pragma unroll
          for (int jb = 0; jb < JBA; ++jb)
            a_[jb] = *(const short8v*)(abase + sv * 64 + jb * 16);
#pragma unroll
          for (int jb = 0; jb < JBA; ++jb) {
            acc[0][jb] = __builtin_amdgcn_mfma_f32_16x16x32_bf16(a_[jb], b0, acc[0][jb], 0, 0, 0);
            acc[1][jb] = __builtin_amdgcn_mfma_f32_16x16x32_bf16(a_[jb], b1, acc[1][jb], 0, 0, 0);
          }
        }
      }
    }
    asm volatile("s_waitcnt vmcnt(0)" ::: "memory");
    __builtin_amdgcn_sched_barrier(0);
    __builtin_amdgcn_s_barrier();
    __builtin_amdgcn_sched_barrier(0);
  }

  if (act) {
    float esum = 0.0f;
#pragma unroll
    for (int g = 0; g < 2; ++g)
#pragma unroll
      for (int jb = 0; jb < JBA; ++jb) {
        int j = sig + 8 * (wv * JBA + jb);
#pragma unroll
        for (int r2 = 0; r2 < 4; ++r2) {
          int i = i0 + 16 * g + 4 * lg + r2;
          float v = acc[g][jb][r2];
          esum += (i < HOUT && j < HOUT) ? v * v : 0.0f;
        }
      }
    esum += __shfl_xor(esum, 16, 64);
    esum += __shfl_xor(esum, 32, 64);
    if (lg == 0) atomicAdd(&E[SIDX * 256 + n * 16 + lr], esum);
  }
}

// Block ranges (bases all multiples of 8 so bl&7 == blockIdx%8 -> XCD):
//  s3: [0,256)  s2: [256,896)  s1: [896,1792)  s0: [1792,2816)
__global__ __launch_bounds__(512, 2) void conv_mfma_kernel(
    const unsigned short* __restrict__ xb, const unsigned short* __restrict__ wp,
    float* __restrict__ E) {
  extern __shared__ char lds[];
  int b = blockIdx.x;
  if (b < 256) {
    conv_scale<193, 7, 2, 4, 64, 2, WOFF3, 3>(b, xb, wp, E, lds);
  } else if (b < 896) {
    conv_scale<97, 4, 4, 5, 160, 5, WOFF2, 2>(b - 256, xb, wp, E, lds);
  } else if (b < 1792) {
    conv_scale<49, 2, 4, 7, 208, 7, WOFF1, 1>(b - 896, xb, wp, E, lds);
  } else {
    conv_scale<25, 1, 4, 8, 232, 8, WOFF0, 0>(b - 1792, xb, wp, E, lds);
  }
}

// ---------------------------------------------------------------------------
// out[n][c][s] = (E[s][n][c] + E[s][n][c+8]) / (Hout_s^2 * scale_s)
// ---------------------------------------------------------------------------
__global__ void finalize_kernel(const float* __restrict__ E, float* __restrict__ out) {
  int idx = threadIdx.x;
  if (idx >= 512) return;
  int s = idx & 3, c = (idx >> 2) & 7, n = idx >> 5;
  float denom;
  if (s == 0)      denom = 53824.0f;    // 1*232^2
  else if (s == 1) denom = 86528.0f;    // 2*208^2
  else if (s == 2) denom = 102400.0f;   // 4*160^2
  else             denom = 32768.0f;    // 8*64^2
  out[idx] = (E[s * 256 + n * 16 + c] + E[s * 256 + n * 16 + c + 8]) / denom;
}

extern "C" void kernel_launch(void* const* d_in, const int* in_sizes, int n_in,
                              void* d_out, int out_size, void* d_ws, size_t ws_size,
                              hipStream_t stream) {
  const float* x = (const float*)d_in[0];
  const float* w[4] = {(const float*)d_in[1], (const float*)d_in[2],
                       (const float*)d_in[3], (const float*)d_in[4]};
  static const int Ks[4]   = {25, 49, 97, 193};
  static const int NSVs[4] = {1, 2, 4, 7};
  static const unsigned wOff[4] = {WOFF0, WOFF1, WOFF2, WOFF3};

  char* wsb = (char*)d_ws;
  float* E = (float*)wsb;                                   // 4 KB
  __hip_bfloat16* xb = (__hip_bfloat16*)(wsb + 4096);       // 2 MB
  unsigned short* wp = (unsigned short*)(wsb + 4096 + (size_t)XB_ELEMS * 2);

  hipMemsetAsync(E, 0, 1024 * sizeof(float), stream);
  xconvert_kernel<<<(XB_ELEMS + 255) / 256, 256, 0, stream>>>(x, xb);
  for (int s = 0; s < 4; ++s) {
    int total = 8 * (Ks[s] + 32) * NSVs[s] * 512;
    wpack_kernel<<<(total + 255) / 256, 256, 0, stream>>>(w[s], wp + wOff[s],
                                                          Ks[s], NSVs[s], total);
  }
  conv_mfma_kernel<<<2816, 512, 2 * BBUF, stream>>>((const unsigned short*)xb, wp, E);
  finalize_kernel<<<1, 512, 0, stream>>>(E, (float*)d_out);
}